// Round 3
// baseline (153.129 us; speedup 1.0000x reference)
//
#include <hip/hip_runtime.h>

// ROI max pooling, matching the JAX reference:
//   img:  (1, 200, 200, 512) fp32, NHWC
//   rois: (1, 128, 4) fp32 as (x, y, w, h) in feature-map pixels
//   pool: 7
// out: (1, 128, 7, 7, 512) fp32
//
// Bin boundaries replicate  int(x + k*(w/P))  in strict IEEE fp32
// (separate div/mul/add, no FMA contraction) so the integer pixel ranges
// match the reference exactly; the max over identical pixel sets is then
// bitwise identical.
//
// R5: locality attack. R2-R4 invariance (ILP x4, waves x4 -> dur const)
// proves a read-throughput wall: ~40 lines in flight per CU at ~450cyc
// avg miss latency (MSHR-class limit), so BW only improves if avg
// latency drops, i.e. more L2 hits. Default round-robin dispatch
// scatters each ROI's bins + overlapping ROIs across all 8 XCD L2s
// (FETCH 143MB ~ 1.75x image). Fix: Morton-sort ROIs by center (tiny
// O(n^2) rank in LDS per block, bitwise-neutral: only remaps block->ROI)
// and chunk 16 consecutive spatial ranks per XCD so each XCD's L2 works
// a compact image band and cross-ROI reuse hits L2 instead of LLC/HBM.

#define IMG_H 200
#define IMG_W 200
#define IMG_C 512
#define C4 (IMG_C / 4)   // 128 float4 slots per pixel
#define POOL 7
#define NROI 128
#define PLANES 4         // pixel-lanes per block
#define NXCD 8
#define NBIN (POOL * POOL)
#define ROIS_PER_XCD (NROI / NXCD)          // 16
// grid = NROI*NBIN = 6272 = NXCD * 784 exactly

typedef float f4v __attribute__((ext_vector_type(4)));

__device__ __forceinline__ float4 max4(float4 a, float4 b) {
    return make_float4(fmaxf(a.x, b.x), fmaxf(a.y, b.y),
                       fmaxf(a.z, b.z), fmaxf(a.w, b.w));
}

// spread low 8 bits: b7..b0 -> 0b0b0b0b... (Morton helper)
__device__ __forceinline__ unsigned spread8(unsigned x) {
    x &= 0xFFu;
    x = (x | (x << 4)) & 0x0F0Fu;
    x = (x | (x << 2)) & 0x3333u;
    x = (x | (x << 1)) & 0x5555u;
    return x;
}

__global__ __launch_bounds__(PLANES * 128, 8) void roi_pool_kernel(
    const float* __restrict__ img,
    const float* __restrict__ rois,
    float* __restrict__ out)
{
    __shared__ unsigned short s_key[NROI];
    __shared__ int s_roi;
    __shared__ float4 red[PLANES - 1][C4];

    const int tid = threadIdx.x;

    // XCD-chunked spatial rank: consecutive blockIdx round-robin XCDs,
    // so xcd = bid&7; each XCD owns 16 consecutive Morton ranks.
    const int xcd  = blockIdx.x & (NXCD - 1);
    const int ixcd = blockIdx.x >> 3;            // 0..783
    const int rank = xcd * ROIS_PER_XCD + ixcd / NBIN;
    const int bin  = ixcd % NBIN;

    // --- Morton rank of all 128 ROIs (redundant per block, ~O(128) per thread)
    if (tid < NROI) {
        const float rx = rois[tid * 4 + 0];
        const float ry = rois[tid * 4 + 1];
        const float rw = rois[tid * 4 + 2];
        const float rh = rois[tid * 4 + 3];
        const unsigned cx = (unsigned)(int)(rx + 0.5f * rw);   // 0..199
        const unsigned cy = (unsigned)(int)(ry + 0.5f * rh);
        s_key[tid] = (unsigned short)((spread8(cy) << 1) | spread8(cx));
    }
    __syncthreads();
    if (tid < NROI) {
        const unsigned my = s_key[tid];
        int r = 0;
        #pragma unroll 8
        for (int u = 0; u < NROI; ++u) {
            const unsigned ku = s_key[u];
            r += (int)((ku < my) | ((ku == my) & (u < tid)));  // tie-break: index
        }
        if (r == rank) s_roi = tid;                // exactly one writer
    }
    __syncthreads();
    const int roi = s_roi;

    const int jy = bin / POOL;
    const int ix = bin % POOL;

    const float rx = rois[roi * 4 + 0];
    const float ry = rois[roi * 4 + 1];
    const float rw = rois[roi * 4 + 2];
    const float rh = rois[roi * 4 + 3];

    // Strict fp32, no contraction: s = w/P; b[k] = int(x + k*s)
    const float sx = __fdiv_rn(rw, 7.0f);
    const float sy = __fdiv_rn(rh, 7.0f);
    const int x1 = (int)__fadd_rn(rx, __fmul_rn((float)ix,       sx));
    const int x2 = (int)__fadd_rn(rx, __fmul_rn((float)(ix + 1), sx));
    const int y1 = (int)__fadd_rn(ry, __fmul_rn((float)jy,       sy));
    const int y2 = (int)__fadd_rn(ry, __fmul_rn((float)(jy + 1), sy));

    const int c4 = tid & 127;               // channel quad
    const int p  = tid >> 7;                // pixel-lane 0..3
    const float4* __restrict__ img4 = (const float4*)img;

    const int bw = x2 - x1;                 // >= 1 by problem construction
    const int bh = y2 - y1;
    const int area = bw * bh;
    (void)bh;

    const float4 NEG = make_float4(-INFINITY, -INFINITY, -INFINITY, -INFINITY);
    float4 m = NEG;

    // Lane p handles linearized bin pixels p, p+4, p+8, ... (row-major in bin).
    int dx = p, dy = 0;
    while (dx >= bw) { dx -= bw; ++dy; }    // p<4, cheap init
    #pragma unroll 2
    for (int i = p; i < area; i += PLANES) {
        const size_t px = (size_t)(y1 + dy) * IMG_W + (size_t)(x1 + dx);
        m = max4(m, img4[px * C4 + c4]);
        dx += PLANES;
        while (dx >= bw) { dx -= bw; ++dy; }
    }

    // Cross-lane (p) reduction via LDS. Lanes with no pixels hold -INF
    // (identity for max); lane 0 always has >=1 pixel.
    if (p > 0) red[p - 1][c4] = m;
    __syncthreads();
    if (p == 0) {
        m = max4(m, red[0][c4]);
        m = max4(m, red[1][c4]);
        m = max4(m, red[2][c4]);

        float4* __restrict__ out4 = (float4*)out;
        f4v* __restrict__ dst =
            (f4v*)&out4[((size_t)(roi * POOL + jy) * POOL + ix) * C4 + c4];
        __builtin_nontemporal_store(*(const f4v*)&m, dst);
    }
}

extern "C" void kernel_launch(void* const* d_in, const int* in_sizes, int n_in,
                              void* d_out, int out_size, void* d_ws, size_t ws_size,
                              hipStream_t stream) {
    (void)in_sizes; (void)n_in; (void)d_ws; (void)ws_size; (void)out_size;
    const float* img  = (const float*)d_in[0];
    const float* rois = (const float*)d_in[1];
    // d_in[2] is pool_size (=7), hardcoded.
    float* out = (float*)d_out;

    dim3 grid(NROI * NBIN);
    dim3 block(PLANES * 128);
    roi_pool_kernel<<<grid, block, 0, stream>>>(img, rois, out);
}